// Round 5
// baseline (806.412 us; speedup 1.0000x reference)
//
#include <hip/hip_runtime.h>
#include <cmath>

// ---------------------------------------------------------------------------
// 6x (conv3x3+BN+ReLU) -> LSTM(4096->256) over S=64 -> tanh(linear). fp32.
// R5: GEMM re-tiled 128x64 (8x4/thread), split-K=8 -> 1024 blocks, 16
// waves/CU (R4: 4x4/thread, 2 blk/CU, VALUBusy 47% = stall-bound).
// All 6 BN-fold dispatches fused into one kernel (launch overhead).
// ---------------------------------------------------------------------------

__device__ __forceinline__ float sigmoidf_(float x) { return 1.f / (1.f + expf(-x)); }

// ---------------- fold BN into conv weights (all layers, one dispatch) -----
// wf layout: [ic][OC][12] (9 taps padded to 12 for aligned b128 LDS reads)
struct FoldPack {
  const float *w[6], *g[6], *b[6], *m[6], *v[6];
  float *wf[6], *bias[6];
  int oc[6], ic[6];
};

__global__ __launch_bounds__(256) void fold_all(FoldPack p) {
  const int layer = blockIdx.y;
  const int OC = p.oc[layer], IC = p.ic[layer];
  const int total = OC * IC * 9;
  const float* w = p.w[layer];
  float* wf = p.wf[layer];
  for (int i = blockIdx.x * 256 + threadIdx.x; i < total; i += gridDim.x * 256) {
    int oc = i / (IC * 9);
    int r  = i % (IC * 9);
    int ic = r / 9;
    int k  = r % 9;
    float inv = p.g[layer][oc] / sqrtf(p.v[layer][oc] + 1e-5f);
    wf[(ic * OC + oc) * 12 + k] = w[i] * inv;
  }
  if (blockIdx.x == 0) {
    int i = threadIdx.x;
    if (i < OC) {
      float inv = p.g[layer][i] / sqrtf(p.v[layer][i] + 1e-5f);
      p.bias[layer][i] = p.b[layer][i] - p.m[layer][i] * inv;
    }
  }
}

// ---------------- direct conv + bias + relu ----------------
// PIW = IW+4 so row bases are 16B-aligned and every thread's tap window
// [xb .. xb+SPAN) sits inside NW aligned float4s (static lane selection).
// SPLITY: blocks per image (row split). NIMG: images per block (weight reuse).
template<int IC, int OC, int IH, int IW, int STRIDE, int ICC, int TPOS,
         int SPLITY, int NIMG>
__global__ __launch_bounds__(256, 2) void conv_bn_relu(
    const float* __restrict__ in, const float* __restrict__ wf,
    const float* __restrict__ bias, float* __restrict__ out)
{
  constexpr int OH = IH / STRIDE, OW = IW / STRIDE;
  constexpr int OHB = OH / SPLITY;                       // out rows per block
  constexpr int RIH = (SPLITY == 1) ? (IH + 2) : ((OHB - 1) * STRIDE + 3);
  constexpr int PIW = IW + 4;                            // mult of 4
  constexpr int PLANE = RIH * PIW;
  constexpr int NPOS = OHB * OW;
  constexpr int WORKERS = NPOS / TPOS;
  constexpr int GROUPS = 256 / WORKERS;
  constexpr int TOC = OC / GROUPS;
  static_assert(GROUPS * TOC == OC && WORKERS * GROUPS == 256, "bad tiling");
  constexpr int SPAN = (TPOS - 1) * STRIDE + 3;
  constexpr int NW = (SPAN + 3) / 4;                     // float4s per window row

  __shared__ float s_in[NIMG * IC * PLANE];
  __shared__ float s_w[ICC * OC * 12];
  __shared__ float s_bias[OC];

  const int tid = threadIdx.x;
  const int n0    = (SPLITY == 1) ? blockIdx.x * NIMG : blockIdx.x / SPLITY;
  const int split = (SPLITY == 1) ? 0 : blockIdx.x % SPLITY;
  const int ry0 = split * OHB;               // global out-row offset
  const int r0  = ry0 * STRIDE - 1;          // input row mapped to LDS row 0
  // valid input-row range [rv0, rv1] clipped to the image (runtime per split)
  const int rv0 = (r0 < 0) ? 0 : r0;
  const int rv1e = r0 + RIH - 1;
  const int rv1 = (rv1e > IH - 1) ? (IH - 1) : rv1e;
  const int VRr = rv1 - rv0 + 1;

  for (int i = tid; i < NIMG * IC * PLANE; i += 256) s_in[i] = 0.f;
  if (tid < OC) s_bias[tid] = bias[tid];
  __syncthreads();                           // memset before interior writes

  // stage interior: float4 global read -> 4 scalar LDS writes (col offset +1)
  constexpr int ROWF4 = IW / 4;
  const int NSTG = NIMG * IC * VRr * ROWF4;
  for (int i = tid; i < NSTG; i += 256) {
    int rw = i % ROWF4;
    int t  = i / ROWF4;
    int row = t % VRr;
    int ci  = t / VRr;                       // img*IC + ic
    int img = ci / IC, ic = ci % IC;
    int giy = rv0 + row;
    float4 val = *(const float4*)(in + (((size_t)(n0 + img) * IC + ic) * IH + giy) * IW + rw * 4);
    float* dst = &s_in[(ci * RIH + (giy - r0)) * PIW + 1 + rw * 4];
    dst[0] = val.x; dst[1] = val.y; dst[2] = val.z; dst[3] = val.w;
  }
  // first chunk's __syncthreads covers staging

  const int worker = tid % WORKERS;
  const int group  = tid / WORKERS;
  const int pos0 = worker * TPOS;
  const int oy  = pos0 / OW;
  const int ox0 = pos0 % OW;
  const int xb  = ox0 * STRIDE;              // aligned window start (mult of 4)

  float acc[NIMG][TOC][TPOS];
  #pragma unroll
  for (int im = 0; im < NIMG; ++im)
    #pragma unroll
    for (int a = 0; a < TOC; ++a)
      #pragma unroll
      for (int p = 0; p < TPOS; ++p) acc[im][a][p] = 0.f;

  for (int ic0 = 0; ic0 < IC; ic0 += ICC) {
    __syncthreads();
    constexpr int WV = ICC * OC * 12 / 4;
    const float4* wsrc = reinterpret_cast<const float4*>(wf + (size_t)ic0 * OC * 12);
    for (int i = tid; i < WV; i += 256)
      reinterpret_cast<float4*>(s_w)[i] = wsrc[i];
    __syncthreads();

    for (int icl = 0; icl < ICC; ++icl) {
      float win[NIMG][3][NW * 4];
      #pragma unroll
      for (int im = 0; im < NIMG; ++im)
        #pragma unroll
        for (int ky = 0; ky < 3; ++ky) {
          const float4* wp4 = (const float4*)
            &s_in[((im * IC + ic0 + icl) * RIH + oy * STRIDE + ky) * PIW + xb];
          #pragma unroll
          for (int w = 0; w < NW; ++w) {
            float4 t = wp4[w];
            win[im][ky][4*w+0] = t.x; win[im][ky][4*w+1] = t.y;
            win[im][ky][4*w+2] = t.z; win[im][ky][4*w+3] = t.w;
          }
        }
      #pragma unroll
      for (int oc = 0; oc < TOC; ++oc) {
        const float4* wp = (const float4*)&s_w[(icl * OC + group * TOC + oc) * 12];
        float4 w0 = wp[0], w1 = wp[1], w2 = wp[2];
        const float wr[9] = {w0.x, w0.y, w0.z, w0.w, w1.x, w1.y, w1.z, w1.w, w2.x};
        #pragma unroll
        for (int im = 0; im < NIMG; ++im)
          #pragma unroll
          for (int p = 0; p < TPOS; ++p)
            #pragma unroll
            for (int ky = 0; ky < 3; ++ky)
              #pragma unroll
              for (int kx = 0; kx < 3; ++kx)
                acc[im][oc][p] = fmaf(win[im][ky][p * STRIDE + kx],
                                      wr[ky * 3 + kx], acc[im][oc][p]);
      }
    }
  }

  #pragma unroll
  for (int im = 0; im < NIMG; ++im) {
    float* outN = out + (size_t)(n0 + im) * (OC * OH * OW);
    #pragma unroll
    for (int oc = 0; oc < TOC; ++oc) {
      const int oco = group * TOC + oc;
      const float bb = s_bias[oco];
      float* op = outN + ((size_t)oco * OH + (ry0 + oy)) * OW + ox0;
      #pragma unroll
      for (int vq = 0; vq < TPOS / 4; ++vq) {
        float4 val;
        val.x = fmaxf(acc[im][oc][vq*4+0] + bb, 0.f);
        val.y = fmaxf(acc[im][oc][vq*4+1] + bb, 0.f);
        val.z = fmaxf(acc[im][oc][vq*4+2] + bb, 0.f);
        val.w = fmaxf(acc[im][oc][vq*4+3] + bb, 0.f);
        *reinterpret_cast<float4*>(op + vq * 4) = val;
      }
    }
  }
}

// ---------------- Xg partials: split-K GEMM (R5) ----------------
// M=1024 (128-tiles), N=1024 (64-tiles), K=4096 in 8 slices of 512.
// 256 threads, 8x4 outputs/thread (32 FMA : 3 ds_read_b128 per k).
// grid 16x8x8 = 1024 blocks -> 4 blocks/CU, 16 waves/CU.
__global__ __launch_bounds__(256, 4) void gemm_xg(
    const float* __restrict__ feats, const float* __restrict__ w_ih,
    float* __restrict__ part)
{
  __shared__ float s_a[2][16][132];        // 128 + 4 pad
  __shared__ float s_b[2][16][68];
  const int tid = threadIdx.x;
  const int col0 = blockIdx.x * 64;
  const int row0 = blockIdx.y * 128;
  const int kbase = blockIdx.z * 512;
  float* outp = part + (size_t)blockIdx.z * 1048576;

  // A staging: row lrowA = tid>>1 (0..127), k-half kh = tid&1 -> 8 floats
  const int lrowA = tid >> 1;
  const int kh = tid & 1;
  const int rA = row0 + lrowA;
  const int nA = (rA & 15) * 64 + (rA >> 4);   // xg row s*16+b <- image b*64+s
  const float* aptr = feats + (size_t)nA * 4096 + kbase + kh * 8;

  // B staging: row lrowB = tid>>2 (0..63), kq = tid&3 -> 4 floats
  const int lrowB = tid >> 2;
  const int kq = tid & 3;
  const float* bptr = w_ih + (size_t)(col0 + lrowB) * 4096 + kbase + kq * 4;

  const int tr = tid >> 4;   // 0..15 -> rows tr*8 ..
  const int tc = tid & 15;   // 0..15 -> cols tc*4 ..

  float acc[8][4] = {};

  float4 a0 = *(const float4*)(aptr);
  float4 a1 = *(const float4*)(aptr + 4);
  float4 bv = *(const float4*)(bptr);
  {
    int ka = kh * 8;
    s_a[0][ka+0][lrowA] = a0.x; s_a[0][ka+1][lrowA] = a0.y;
    s_a[0][ka+2][lrowA] = a0.z; s_a[0][ka+3][lrowA] = a0.w;
    s_a[0][ka+4][lrowA] = a1.x; s_a[0][ka+5][lrowA] = a1.y;
    s_a[0][ka+6][lrowA] = a1.z; s_a[0][ka+7][lrowA] = a1.w;
    int kb = kq * 4;
    s_b[0][kb+0][lrowB] = bv.x; s_b[0][kb+1][lrowB] = bv.y;
    s_b[0][kb+2][lrowB] = bv.z; s_b[0][kb+3][lrowB] = bv.w;
  }
  __syncthreads();

  for (int kc = 0; kc < 32; ++kc) {
    const int cur = kc & 1;
    if (kc < 31) {
      a0 = *(const float4*)(aptr + (size_t)(kc + 1) * 16);
      a1 = *(const float4*)(aptr + (size_t)(kc + 1) * 16 + 4);
      bv = *(const float4*)(bptr + (size_t)(kc + 1) * 16);
    }
    #pragma unroll
    for (int k = 0; k < 16; ++k) {
      float4 x0 = *(const float4*)&s_a[cur][k][tr * 8];
      float4 x1 = *(const float4*)&s_a[cur][k][tr * 8 + 4];
      float4 y  = *(const float4*)&s_b[cur][k][tc * 4];
      float ar[8] = {x0.x, x0.y, x0.z, x0.w, x1.x, x1.y, x1.z, x1.w};
      float br[4] = {y.x, y.y, y.z, y.w};
      #pragma unroll
      for (int i = 0; i < 8; ++i)
        #pragma unroll
        for (int jj = 0; jj < 4; ++jj)
          acc[i][jj] = fmaf(ar[i], br[jj], acc[i][jj]);
    }
    if (kc < 31) {
      int nb = cur ^ 1;
      int ka = kh * 8;
      s_a[nb][ka+0][lrowA] = a0.x; s_a[nb][ka+1][lrowA] = a0.y;
      s_a[nb][ka+2][lrowA] = a0.z; s_a[nb][ka+3][lrowA] = a0.w;
      s_a[nb][ka+4][lrowA] = a1.x; s_a[nb][ka+5][lrowA] = a1.y;
      s_a[nb][ka+6][lrowA] = a1.z; s_a[nb][ka+7][lrowA] = a1.w;
      int kb = kq * 4;
      s_b[nb][kb+0][lrowB] = bv.x; s_b[nb][kb+1][lrowB] = bv.y;
      s_b[nb][kb+2][lrowB] = bv.z; s_b[nb][kb+3][lrowB] = bv.w;
    }
    __syncthreads();
  }

  #pragma unroll
  for (int i = 0; i < 8; ++i) {
    int rr = row0 + tr * 8 + i;
    float4 o;
    o.x = acc[i][0]; o.y = acc[i][1]; o.z = acc[i][2]; o.w = acc[i][3];
    *(float4*)(outp + (size_t)rr * 1024 + col0 + tc * 4) = o;
  }
}

// xg = sum_z p[z] + (b_ih + b_hh)
__global__ __launch_bounds__(256) void reduce_xg(
    const float* __restrict__ p, const float* __restrict__ b_ih,
    const float* __restrict__ b_hh, float* __restrict__ xg)
{
  int i = blockIdx.x * 256 + threadIdx.x;          // float4 index, 262144 total
  float4 s = {0.f, 0.f, 0.f, 0.f};
  #pragma unroll
  for (int z = 0; z < 8; ++z) {
    float4 a = ((const float4*)p)[(size_t)z * 262144 + i];
    s.x += a.x; s.y += a.y; s.z += a.z; s.w += a.w;
  }
  int cb = i & 255;                                 // column float4 index
  float4 bi = ((const float4*)b_ih)[cb];
  float4 bh = ((const float4*)b_hh)[cb];
  float4 o;
  o.x = s.x + bi.x + bh.x;
  o.y = s.y + bi.y + bh.y;
  o.z = s.z + bi.z + bh.z;
  o.w = s.w + bi.w + bh.w;
  ((float4*)xg)[i] = o;
}

// ---------------- persistent LSTM recurrence ----------------
// 64 blocks x 1024 threads; block = (batch b, slice g). h values published as
// (tag=step+1, value) 64-bit pairs via relaxed agent-scope atomics; consumers
// spin directly on the pairs they need -- no counters, no fences, one one-way
// coherence hop per step. ws poison 0xAAAAAAAA never matches tags 1..64.
__global__ __launch_bounds__(1024) void lstm_kernel(
    const float* __restrict__ xg, const float* __restrict__ w_hh,
    float* __restrict__ hs, unsigned long long* __restrict__ hpair)
{
  const int b = blockIdx.x >> 2;
  const int g = blockIdx.x & 3;
  const int tid = threadIdx.x;
  const int r = tid >> 2;          // 0..255 gate-row
  const int q = tid & 3;           // k-quarter
  const int gate = r >> 6;
  const int jl = r & 63;
  const int j = g * 64 + jl;

  float4 wv[16];
  {
    const float4* wrow = (const float4*)(w_hh + ((size_t)(gate * 256 + j)) * 256 + q * 64);
    #pragma unroll
    for (int k = 0; k < 16; ++k) wv[k] = wrow[k];
  }

  __shared__ float s_h[4 * 72];
  __shared__ float s_gates[4][64];
  float c_reg = 0.f;

  for (int s = 0; s < 64; ++s) {
    float xv = 0.f;
    if (q == 0) xv = xg[(size_t)(s * 16 + b) * 1024 + gate * 256 + j];  // in flight during spin
    float gv = 0.f;
    if (s > 0) {
      if (tid < 256) {
        const unsigned long long* src = hpair + ((size_t)(s - 1) * 16 + b) * 256 + tid;
        unsigned long long pv;
        do {
          pv = __hip_atomic_load(src, __ATOMIC_RELAXED, __HIP_MEMORY_SCOPE_AGENT);
        } while ((unsigned int)(pv >> 32) != (unsigned int)s);
        s_h[(tid >> 6) * 72 + (tid & 63)] = __uint_as_float((unsigned int)pv);
      }
      __syncthreads();
      const float4* hp = (const float4*)&s_h[q * 72];
      float p = 0.f;
      #pragma unroll
      for (int k = 0; k < 16; ++k) {
        float4 h4 = hp[k];
        p = fmaf(h4.x, wv[k].x, p);
        p = fmaf(h4.y, wv[k].y, p);
        p = fmaf(h4.z, wv[k].z, p);
        p = fmaf(h4.w, wv[k].w, p);
      }
      p += __shfl_xor(p, 1);
      p += __shfl_xor(p, 2);
      gv = p;
    }
    if (q == 0) s_gates[gate][jl] = gv + xv;
    __syncthreads();
    if (tid < 64) {
      float gi = s_gates[0][tid], gf = s_gates[1][tid];
      float gg = s_gates[2][tid], go = s_gates[3][tid];
      float cn = sigmoidf_(gf) * c_reg + sigmoidf_(gi) * tanhf(gg);
      c_reg = cn;
      float hv = sigmoidf_(go) * tanhf(cn);
      hs[(size_t)s * 4096 + b * 256 + g * 64 + tid] = hv;      // plain, for cls
      unsigned long long pv =
          ((unsigned long long)(unsigned int)(s + 1) << 32) | __float_as_uint(hv);
      __hip_atomic_store(hpair + ((size_t)s * 16 + b) * 256 + g * 64 + tid, pv,
                         __ATOMIC_RELAXED, __HIP_MEMORY_SCOPE_AGENT);
    }
    // no end-of-step barrier: next-iter s_h/s_gates writes are ordered behind
    // this iter's barriers; peer data exchange is tag-driven.
  }
}

// ---------------- classifier head ----------------
__global__ __launch_bounds__(64) void cls_kernel(
    const float* __restrict__ hs, const float* __restrict__ cw,
    const float* __restrict__ cb, float* __restrict__ out)
{
  const int id = blockIdx.x;             // b*53 + t
  const int b = id / 53;
  const int t = id % 53;
  const int s = 11 + t;
  const int lane = threadIdx.x;
  float4 hv = ((const float4*)(hs + (size_t)s * 4096 + b * 256))[lane];
  float4 wv = ((const float4*)cw)[lane];
  float p = hv.x * wv.x + hv.y * wv.y + hv.z * wv.z + hv.w * wv.w;
  #pragma unroll
  for (int off = 32; off >= 1; off >>= 1) p += __shfl_xor(p, off);
  if (lane == 0) out[id] = tanhf(p + cb[0]);
}

// ---------------------------------------------------------------------------
extern "C" void kernel_launch(void* const* d_in, const int* in_sizes, int n_in,
                              void* d_out, int out_size, void* d_ws, size_t ws_size,
                              hipStream_t stream)
{
  (void)in_sizes; (void)n_in; (void)out_size; (void)ws_size;
  const float* imgs = (const float*)d_in[0];
  const float* w_ih  = (const float*)d_in[31];
  const float* w_hh  = (const float*)d_in[32];
  const float* b_ih  = (const float*)d_in[33];
  const float* b_hh  = (const float*)d_in[34];
  const float* cls_w = (const float*)d_in[35];
  const float* cls_b = (const float*)d_in[36];
  float* out = (float*)d_out;

  // ws layout (floats): actA(16.78M, reused as gemm partials 8x1.05M) actB
  // (16.78M) xg(1.05M) hs(262K) hpair(524K as u64) wf bias
  float* ws   = (float*)d_ws;
  float* actA = ws;
  float* actB = actA + 16777216;
  float* xg   = actB + 16777216;
  float* hs   = xg + 1048576;
  unsigned long long* hpair = (unsigned long long*)(hs + 262144);
  float* wfp  = hs + 262144 + 524288;
  static const int ocs[6] = {16, 16, 32, 32, 64, 64};
  static const int ics[6] = {3, 16, 16, 32, 32, 64};
  float* wf[6];
  size_t off = 0;
  for (int i = 0; i < 6; ++i) { wf[i] = wfp + off; off += (size_t)ocs[i] * ics[i] * 12; }
  float* biasp = wfp + off;
  float* bias[6];
  for (int i = 0; i < 6; ++i) bias[i] = biasp + i * 64;

  FoldPack fp;
  for (int i = 0; i < 6; ++i) {
    fp.w[i] = (const float*)d_in[1 + 5*i];
    fp.g[i] = (const float*)d_in[2 + 5*i];
    fp.b[i] = (const float*)d_in[3 + 5*i];
    fp.m[i] = (const float*)d_in[4 + 5*i];
    fp.v[i] = (const float*)d_in[5 + 5*i];
    fp.wf[i] = wf[i];
    fp.bias[i] = bias[i];
    fp.oc[i] = ocs[i];
    fp.ic[i] = ics[i];
  }
  fold_all<<<dim3(8, 6), 256, 0, stream>>>(fp);

  //                IC  OC  IH  IW  S  ICC TP SPL NI
  conv_bn_relu< 3, 16, 64, 64, 2,  3, 8, 1, 1><<<1024, 256, 0, stream>>>(imgs,  wf[0], bias[0], actA);
  conv_bn_relu<16, 16, 32, 32, 1,  8, 8, 2, 1><<<2048, 256, 0, stream>>>(actA, wf[1], bias[1], actB);
  conv_bn_relu<16, 32, 32, 32, 2,  8, 4, 2, 1><<<2048, 256, 0, stream>>>(actB, wf[2], bias[2], actA);
  conv_bn_relu<32, 32, 16, 16, 1,  8, 8, 1, 1><<<1024, 256, 0, stream>>>(actA, wf[3], bias[3], actB);
  conv_bn_relu<32, 64, 16, 16, 2,  8, 4, 1, 1><<<1024, 256, 0, stream>>>(actB, wf[4], bias[4], actA);
  conv_bn_relu<64, 64,  8,  8, 1,  4, 8, 1, 2><<< 512, 256, 0, stream>>>(actA, wf[5], bias[5], actB);

  gemm_xg<<<dim3(16, 8, 8), 256, 0, stream>>>(actB, w_ih, actA);   // partials in actA
  reduce_xg<<<1024, 256, 0, stream>>>(actA, b_ih, b_hh, xg);
  lstm_kernel<<<64, 1024, 0, stream>>>(xg, w_hh, hs, hpair);
  cls_kernel<<<848, 64, 0, stream>>>(hs, cls_w, cls_b, out);
}

// Round 6
// 785.377 us; speedup vs baseline: 1.0268x; 1.0268x over previous
//
#include <hip/hip_runtime.h>
#include <cmath>

// ---------------------------------------------------------------------------
// 6x (conv3x3+BN+ReLU) -> LSTM(4096->256) over S=64 -> tanh(linear). fp32.
// R6: conv inner loop restructured (ky-outer, weights [ic][ky][OC][4]) to cut
// live registers below the 128-VGPR launch_bounds cap -- R3/R5 convs held a
// 36-float window + 32-64 acc + weights and almost certainly spilled, which
// is why the b128 rewrite was neutral (~490us all rounds, 26% of FMA floor).
// LSTM blocks remapped (b=bid&15, g=bid>>4) so each batch's 4-block sync
// group shares bid%8 -> same XCD under cyclic dispatch -> L2-local spins.
// ---------------------------------------------------------------------------

__device__ __forceinline__ float sigmoidf_(float x) { return 1.f / (1.f + expf(-x)); }

// ---------------- fold BN into conv weights (all layers, one dispatch) -----
// wf layout: [ic][ky][OC][4]  (3 taps of row ky + pad, 16B-aligned per oc)
struct FoldPack {
  const float *w[6], *g[6], *b[6], *m[6], *v[6];
  float *wf[6], *bias[6];
  int oc[6], ic[6];
};

__global__ __launch_bounds__(256) void fold_all(FoldPack p) {
  const int layer = blockIdx.y;
  const int OC = p.oc[layer], IC = p.ic[layer];
  const int total = OC * IC * 9;
  const float* w = p.w[layer];
  float* wf = p.wf[layer];
  for (int i = blockIdx.x * 256 + threadIdx.x; i < total; i += gridDim.x * 256) {
    int oc = i / (IC * 9);
    int r  = i % (IC * 9);
    int ic = r / 9;
    int k  = r % 9;
    int ky = k / 3, kx = k % 3;
    float inv = p.g[layer][oc] / sqrtf(p.v[layer][oc] + 1e-5f);
    wf[(((ic * 3 + ky) * OC) + oc) * 4 + kx] = w[i] * inv;
  }
  if (blockIdx.x == 0) {
    int i = threadIdx.x;
    if (i < OC) {
      float inv = p.g[layer][i] / sqrtf(p.v[layer][i] + 1e-5f);
      p.bias[layer][i] = p.b[layer][i] - p.m[layer][i] * inv;
    }
  }
}

// ---------------- direct conv + bias + relu ----------------
// PIW = IW+4 so row bases are 16B-aligned and every thread's tap window
// [xb .. xb+SPAN) sits inside NW aligned float4s (static lane selection).
// SPLITY: blocks per image (row split). NIMG: images per block (weight reuse).
// Inner loops: icl -> im -> ky -> oc -> p. Live set: acc + 1 window row +
// 1 float4 weight (no spill under the 128-VGPR cap).
template<int IC, int OC, int IH, int IW, int STRIDE, int ICC, int TPOS,
         int SPLITY, int NIMG>
__global__ __launch_bounds__(256, 2) void conv_bn_relu(
    const float* __restrict__ in, const float* __restrict__ wf,
    const float* __restrict__ bias, float* __restrict__ out)
{
  constexpr int OH = IH / STRIDE, OW = IW / STRIDE;
  constexpr int OHB = OH / SPLITY;                       // out rows per block
  constexpr int RIH = (SPLITY == 1) ? (IH + 2) : ((OHB - 1) * STRIDE + 3);
  constexpr int PIW = IW + 4;                            // mult of 4
  constexpr int PLANE = RIH * PIW;
  constexpr int NPOS = OHB * OW;
  constexpr int WORKERS = NPOS / TPOS;
  constexpr int GROUPS = 256 / WORKERS;
  constexpr int TOC = OC / GROUPS;
  static_assert(GROUPS * TOC == OC && WORKERS * GROUPS == 256, "bad tiling");
  constexpr int SPAN = (TPOS - 1) * STRIDE + 3;
  constexpr int NW = (SPAN + 3) / 4;                     // float4s per window row

  __shared__ float s_in[NIMG * IC * PLANE];
  __shared__ float s_w[ICC * OC * 12];
  __shared__ float s_bias[OC];

  const int tid = threadIdx.x;
  const int n0    = (SPLITY == 1) ? blockIdx.x * NIMG : blockIdx.x / SPLITY;
  const int split = (SPLITY == 1) ? 0 : blockIdx.x % SPLITY;
  const int ry0 = split * OHB;               // global out-row offset
  const int r0  = ry0 * STRIDE - 1;          // input row mapped to LDS row 0
  // valid input-row range [rv0, rv1] clipped to the image (runtime per split)
  const int rv0 = (r0 < 0) ? 0 : r0;
  const int rv1e = r0 + RIH - 1;
  const int rv1 = (rv1e > IH - 1) ? (IH - 1) : rv1e;
  const int VRr = rv1 - rv0 + 1;

  for (int i = tid; i < NIMG * IC * PLANE; i += 256) s_in[i] = 0.f;
  if (tid < OC) s_bias[tid] = bias[tid];
  __syncthreads();                           // memset before interior writes

  // stage interior: float4 global read -> 4 scalar LDS writes (col offset +1)
  constexpr int ROWF4 = IW / 4;
  const int NSTG = NIMG * IC * VRr * ROWF4;
  for (int i = tid; i < NSTG; i += 256) {
    int rw = i % ROWF4;
    int t  = i / ROWF4;
    int row = t % VRr;
    int ci  = t / VRr;                       // img*IC + ic
    int img = ci / IC, ic = ci % IC;
    int giy = rv0 + row;
    float4 val = *(const float4*)(in + (((size_t)(n0 + img) * IC + ic) * IH + giy) * IW + rw * 4);
    float* dst = &s_in[(ci * RIH + (giy - r0)) * PIW + 1 + rw * 4];
    dst[0] = val.x; dst[1] = val.y; dst[2] = val.z; dst[3] = val.w;
  }
  // first chunk's __syncthreads covers staging

  const int worker = tid % WORKERS;
  const int group  = tid / WORKERS;
  const int pos0 = worker * TPOS;
  const int oy  = pos0 / OW;
  const int ox0 = pos0 % OW;
  const int xb  = ox0 * STRIDE;              // aligned window start (mult of 4)

  float acc[NIMG][TOC][TPOS];
  #pragma unroll
  for (int im = 0; im < NIMG; ++im)
    #pragma unroll
    for (int a = 0; a < TOC; ++a)
      #pragma unroll
      for (int p = 0; p < TPOS; ++p) acc[im][a][p] = 0.f;

  for (int ic0 = 0; ic0 < IC; ic0 += ICC) {
    __syncthreads();
    constexpr int WV = ICC * OC * 12 / 4;
    const float4* wsrc = reinterpret_cast<const float4*>(wf + (size_t)ic0 * OC * 12);
    for (int i = tid; i < WV; i += 256)
      reinterpret_cast<float4*>(s_w)[i] = wsrc[i];
    __syncthreads();

    for (int icl = 0; icl < ICC; ++icl) {
      #pragma unroll
      for (int im = 0; im < NIMG; ++im) {
        const float* sI = &s_in[(im * IC + ic0 + icl) * PLANE];
        #pragma unroll
        for (int ky = 0; ky < 3; ++ky) {
          float row[NW * 4];
          {
            const float4* rp4 = (const float4*)&sI[(oy * STRIDE + ky) * PIW + xb];
            #pragma unroll
            for (int w = 0; w < NW; ++w) {
              float4 t = rp4[w];
              row[4*w+0] = t.x; row[4*w+1] = t.y;
              row[4*w+2] = t.z; row[4*w+3] = t.w;
            }
          }
          #pragma unroll
          for (int oc = 0; oc < TOC; ++oc) {
            float4 w4 = ((const float4*)s_w)[(icl * 3 + ky) * OC + group * TOC + oc];
            #pragma unroll
            for (int p = 0; p < TPOS; ++p) {
              float a = acc[im][oc][p];
              a = fmaf(row[p * STRIDE + 0], w4.x, a);
              a = fmaf(row[p * STRIDE + 1], w4.y, a);
              a = fmaf(row[p * STRIDE + 2], w4.z, a);
              acc[im][oc][p] = a;
            }
          }
        }
      }
    }
  }

  #pragma unroll
  for (int im = 0; im < NIMG; ++im) {
    float* outN = out + (size_t)(n0 + im) * (OC * OH * OW);
    #pragma unroll
    for (int oc = 0; oc < TOC; ++oc) {
      const int oco = group * TOC + oc;
      const float bb = s_bias[oco];
      float* op = outN + ((size_t)oco * OH + (ry0 + oy)) * OW + ox0;
      #pragma unroll
      for (int vq = 0; vq < TPOS / 4; ++vq) {
        float4 val;
        val.x = fmaxf(acc[im][oc][vq*4+0] + bb, 0.f);
        val.y = fmaxf(acc[im][oc][vq*4+1] + bb, 0.f);
        val.z = fmaxf(acc[im][oc][vq*4+2] + bb, 0.f);
        val.w = fmaxf(acc[im][oc][vq*4+3] + bb, 0.f);
        *reinterpret_cast<float4*>(op + vq * 4) = val;
      }
    }
  }
}

// ---------------- Xg partials: split-K GEMM ----------------
// M=1024 (128-tiles), N=1024 (64-tiles), K=4096 in 8 slices of 512.
// 256 threads, 8x4 outputs/thread. grid 16x8x8 = 1024 blocks.
__global__ __launch_bounds__(256, 4) void gemm_xg(
    const float* __restrict__ feats, const float* __restrict__ w_ih,
    float* __restrict__ part)
{
  __shared__ float s_a[2][16][132];        // 128 + 4 pad
  __shared__ float s_b[2][16][68];
  const int tid = threadIdx.x;
  const int col0 = blockIdx.x * 64;
  const int row0 = blockIdx.y * 128;
  const int kbase = blockIdx.z * 512;
  float* outp = part + (size_t)blockIdx.z * 1048576;

  const int lrowA = tid >> 1;
  const int kh = tid & 1;
  const int rA = row0 + lrowA;
  const int nA = (rA & 15) * 64 + (rA >> 4);   // xg row s*16+b <- image b*64+s
  const float* aptr = feats + (size_t)nA * 4096 + kbase + kh * 8;

  const int lrowB = tid >> 2;
  const int kq = tid & 3;
  const float* bptr = w_ih + (size_t)(col0 + lrowB) * 4096 + kbase + kq * 4;

  const int tr = tid >> 4;   // 0..15 -> rows tr*8 ..
  const int tc = tid & 15;   // 0..15 -> cols tc*4 ..

  float acc[8][4] = {};

  float4 a0 = *(const float4*)(aptr);
  float4 a1 = *(const float4*)(aptr + 4);
  float4 bv = *(const float4*)(bptr);
  {
    int ka = kh * 8;
    s_a[0][ka+0][lrowA] = a0.x; s_a[0][ka+1][lrowA] = a0.y;
    s_a[0][ka+2][lrowA] = a0.z; s_a[0][ka+3][lrowA] = a0.w;
    s_a[0][ka+4][lrowA] = a1.x; s_a[0][ka+5][lrowA] = a1.y;
    s_a[0][ka+6][lrowA] = a1.z; s_a[0][ka+7][lrowA] = a1.w;
    int kb = kq * 4;
    s_b[0][kb+0][lrowB] = bv.x; s_b[0][kb+1][lrowB] = bv.y;
    s_b[0][kb+2][lrowB] = bv.z; s_b[0][kb+3][lrowB] = bv.w;
  }
  __syncthreads();

  for (int kc = 0; kc < 32; ++kc) {
    const int cur = kc & 1;
    if (kc < 31) {
      a0 = *(const float4*)(aptr + (size_t)(kc + 1) * 16);
      a1 = *(const float4*)(aptr + (size_t)(kc + 1) * 16 + 4);
      bv = *(const float4*)(bptr + (size_t)(kc + 1) * 16);
    }
    #pragma unroll
    for (int k = 0; k < 16; ++k) {
      float4 x0 = *(const float4*)&s_a[cur][k][tr * 8];
      float4 x1 = *(const float4*)&s_a[cur][k][tr * 8 + 4];
      float4 y  = *(const float4*)&s_b[cur][k][tc * 4];
      float ar[8] = {x0.x, x0.y, x0.z, x0.w, x1.x, x1.y, x1.z, x1.w};
      float br[4] = {y.x, y.y, y.z, y.w};
      #pragma unroll
      for (int i = 0; i < 8; ++i)
        #pragma unroll
        for (int jj = 0; jj < 4; ++jj)
          acc[i][jj] = fmaf(ar[i], br[jj], acc[i][jj]);
    }
    if (kc < 31) {
      int nb = cur ^ 1;
      int ka = kh * 8;
      s_a[nb][ka+0][lrowA] = a0.x; s_a[nb][ka+1][lrowA] = a0.y;
      s_a[nb][ka+2][lrowA] = a0.z; s_a[nb][ka+3][lrowA] = a0.w;
      s_a[nb][ka+4][lrowA] = a1.x; s_a[nb][ka+5][lrowA] = a1.y;
      s_a[nb][ka+6][lrowA] = a1.z; s_a[nb][ka+7][lrowA] = a1.w;
      int kb = kq * 4;
      s_b[nb][kb+0][lrowB] = bv.x; s_b[nb][kb+1][lrowB] = bv.y;
      s_b[nb][kb+2][lrowB] = bv.z; s_b[nb][kb+3][lrowB] = bv.w;
    }
    __syncthreads();
  }

  #pragma unroll
  for (int i = 0; i < 8; ++i) {
    int rr = row0 + tr * 8 + i;
    float4 o;
    o.x = acc[i][0]; o.y = acc[i][1]; o.z = acc[i][2]; o.w = acc[i][3];
    *(float4*)(outp + (size_t)rr * 1024 + col0 + tc * 4) = o;
  }
}

// xg = sum_z p[z] + (b_ih + b_hh)
__global__ __launch_bounds__(256) void reduce_xg(
    const float* __restrict__ p, const float* __restrict__ b_ih,
    const float* __restrict__ b_hh, float* __restrict__ xg)
{
  int i = blockIdx.x * 256 + threadIdx.x;          // float4 index, 262144 total
  float4 s = {0.f, 0.f, 0.f, 0.f};
  #pragma unroll
  for (int z = 0; z < 8; ++z) {
    float4 a = ((const float4*)p)[(size_t)z * 262144 + i];
    s.x += a.x; s.y += a.y; s.z += a.z; s.w += a.w;
  }
  int cb = i & 255;                                 // column float4 index
  float4 bi = ((const float4*)b_ih)[cb];
  float4 bh = ((const float4*)b_hh)[cb];
  float4 o;
  o.x = s.x + bi.x + bh.x;
  o.y = s.y + bi.y + bh.y;
  o.z = s.z + bi.z + bh.z;
  o.w = s.w + bi.w + bh.w;
  ((float4*)xg)[i] = o;
}

// ---------------- persistent LSTM recurrence ----------------
// 64 blocks x 1024 threads. Block -> (b = bid&15, g = bid>>4): the 4 blocks
// of batch b are bids {b, b+16, b+32, b+48}, all == b (mod 8) -> same XCD
// under cyclic dispatch -> tag-spin exchange stays in local L2. Mapping is a
// perf heuristic only; tag protocol is correct for any placement.
__global__ __launch_bounds__(1024) void lstm_kernel(
    const float* __restrict__ xg, const float* __restrict__ w_hh,
    float* __restrict__ hs, unsigned long long* __restrict__ hpair)
{
  const int b = blockIdx.x & 15;
  const int g = blockIdx.x >> 4;
  const int tid = threadIdx.x;
  const int r = tid >> 2;          // 0..255 gate-row
  const int q = tid & 3;           // k-quarter
  const int gate = r >> 6;
  const int jl = r & 63;
  const int j = g * 64 + jl;

  float4 wv[16];
  {
    const float4* wrow = (const float4*)(w_hh + ((size_t)(gate * 256 + j)) * 256 + q * 64);
    #pragma unroll
    for (int k = 0; k < 16; ++k) wv[k] = wrow[k];
  }

  __shared__ float s_h[4 * 72];
  __shared__ float s_gates[4][64];
  float c_reg = 0.f;

  for (int s = 0; s < 64; ++s) {
    float xv = 0.f;
    if (q == 0) xv = xg[(size_t)(s * 16 + b) * 1024 + gate * 256 + j];  // in flight during spin
    float gv = 0.f;
    if (s > 0) {
      if (tid < 256) {
        const unsigned long long* src = hpair + ((size_t)(s - 1) * 16 + b) * 256 + tid;
        unsigned long long pv;
        do {
          pv = __hip_atomic_load(src, __ATOMIC_RELAXED, __HIP_MEMORY_SCOPE_AGENT);
        } while ((unsigned int)(pv >> 32) != (unsigned int)s);
        s_h[(tid >> 6) * 72 + (tid & 63)] = __uint_as_float((unsigned int)pv);
      }
      __syncthreads();
      const float4* hp = (const float4*)&s_h[q * 72];
      float p = 0.f;
      #pragma unroll
      for (int k = 0; k < 16; ++k) {
        float4 h4 = hp[k];
        p = fmaf(h4.x, wv[k].x, p);
        p = fmaf(h4.y, wv[k].y, p);
        p = fmaf(h4.z, wv[k].z, p);
        p = fmaf(h4.w, wv[k].w, p);
      }
      p += __shfl_xor(p, 1);
      p += __shfl_xor(p, 2);
      gv = p;
    }
    if (q == 0) s_gates[gate][jl] = gv + xv;
    __syncthreads();
    if (tid < 64) {
      float gi = s_gates[0][tid], gf = s_gates[1][tid];
      float gg = s_gates[2][tid], go = s_gates[3][tid];
      float cn = sigmoidf_(gf) * c_reg + sigmoidf_(gi) * tanhf(gg);
      c_reg = cn;
      float hv = sigmoidf_(go) * tanhf(cn);
      hs[(size_t)s * 4096 + b * 256 + g * 64 + tid] = hv;      // plain, for cls
      unsigned long long pv =
          ((unsigned long long)(unsigned int)(s + 1) << 32) | __float_as_uint(hv);
      __hip_atomic_store(hpair + ((size_t)s * 16 + b) * 256 + g * 64 + tid, pv,
                         __ATOMIC_RELAXED, __HIP_MEMORY_SCOPE_AGENT);
    }
    // no end-of-step barrier: next-iter s_h/s_gates writes are ordered behind
    // this iter's barriers; peer data exchange is tag-driven.
  }
}

// ---------------- classifier head ----------------
__global__ __launch_bounds__(64) void cls_kernel(
    const float* __restrict__ hs, const float* __restrict__ cw,
    const float* __restrict__ cb, float* __restrict__ out)
{
  const int id = blockIdx.x;             // b*53 + t
  const int b = id / 53;
  const int t = id % 53;
  const int s = 11 + t;
  const int lane = threadIdx.x;
  float4 hv = ((const float4*)(hs + (size_t)s * 4096 + b * 256))[lane];
  float4 wv = ((const float4*)cw)[lane];
  float p = hv.x * wv.x + hv.y * wv.y + hv.z * wv.z + hv.w * wv.w;
  #pragma unroll
  for (int off = 32; off >= 1; off >>= 1) p += __shfl_xor(p, off);
  if (lane == 0) out[id] = tanhf(p + cb[0]);
}

// ---------------------------------------------------------------------------
extern "C" void kernel_launch(void* const* d_in, const int* in_sizes, int n_in,
                              void* d_out, int out_size, void* d_ws, size_t ws_size,
                              hipStream_t stream)
{
  (void)in_sizes; (void)n_in; (void)out_size; (void)ws_size;
  const float* imgs = (const float*)d_in[0];
  const float* w_ih  = (const float*)d_in[31];
  const float* w_hh  = (const float*)d_in[32];
  const float* b_ih  = (const float*)d_in[33];
  const float* b_hh  = (const float*)d_in[34];
  const float* cls_w = (const float*)d_in[35];
  const float* cls_b = (const float*)d_in[36];
  float* out = (float*)d_out;

  // ws layout (floats): actA(16.78M, reused as gemm partials 8x1.05M) actB
  // (16.78M) xg(1.05M) hs(262K) hpair(524K as u64) wf bias
  float* ws   = (float*)d_ws;
  float* actA = ws;
  float* actB = actA + 16777216;
  float* xg   = actB + 16777216;
  float* hs   = xg + 1048576;
  unsigned long long* hpair = (unsigned long long*)(hs + 262144);
  float* wfp  = hs + 262144 + 524288;
  static const int ocs[6] = {16, 16, 32, 32, 64, 64};
  static const int ics[6] = {3, 16, 16, 32, 32, 64};
  float* wf[6];
  size_t off = 0;
  for (int i = 0; i < 6; ++i) { wf[i] = wfp + off; off += (size_t)ocs[i] * ics[i] * 12; }
  float* biasp = wfp + off;
  float* bias[6];
  for (int i = 0; i < 6; ++i) bias[i] = biasp + i * 64;

  FoldPack fp;
  for (int i = 0; i < 6; ++i) {
    fp.w[i] = (const float*)d_in[1 + 5*i];
    fp.g[i] = (const float*)d_in[2 + 5*i];
    fp.b[i] = (const float*)d_in[3 + 5*i];
    fp.m[i] = (const float*)d_in[4 + 5*i];
    fp.v[i] = (const float*)d_in[5 + 5*i];
    fp.wf[i] = wf[i];
    fp.bias[i] = bias[i];
    fp.oc[i] = ocs[i];
    fp.ic[i] = ics[i];
  }
  fold_all<<<dim3(8, 6), 256, 0, stream>>>(fp);

  //                IC  OC  IH  IW  S  ICC TP SPL NI
  conv_bn_relu< 3, 16, 64, 64, 2,  3, 8, 1, 1><<<1024, 256, 0, stream>>>(imgs,  wf[0], bias[0], actA);
  conv_bn_relu<16, 16, 32, 32, 1,  8, 8, 2, 1><<<2048, 256, 0, stream>>>(actA, wf[1], bias[1], actB);
  conv_bn_relu<16, 32, 32, 32, 2,  8, 4, 2, 1><<<2048, 256, 0, stream>>>(actB, wf[2], bias[2], actA);
  conv_bn_relu<32, 32, 16, 16, 1,  8, 8, 1, 1><<<1024, 256, 0, stream>>>(actA, wf[3], bias[3], actB);
  conv_bn_relu<32, 64, 16, 16, 2,  8, 4, 1, 1><<<1024, 256, 0, stream>>>(actB, wf[4], bias[4], actA);
  conv_bn_relu<64, 64,  8,  8, 1,  4, 8, 1, 2><<< 512, 256, 0, stream>>>(actA, wf[5], bias[5], actB);

  gemm_xg<<<dim3(16, 8, 8), 256, 0, stream>>>(actB, w_ih, actA);   // partials in actA
  reduce_xg<<<1024, 256, 0, stream>>>(actA, b_ih, b_hh, xg);
  lstm_kernel<<<64, 1024, 0, stream>>>(xg, w_hh, hs, hpair);
  cls_kernel<<<848, 64, 0, stream>>>(hs, cls_w, cls_b, out);
}